// Round 5
// baseline (270.247 us; speedup 1.0000x reference)
//
#include <hip/hip_runtime.h>
#include <hip/hip_bf16.h>
#include <math.h>

#define BB 128   // batch
#define NN 96    // perturbations
#define DD 3072  // C*H*W
#define KK 10    // classes
#define SPL 8    // K-splits = waves per block in k1
#define KST 12   // MFMA K-steps per wave: 3072 / (SPL*32)

typedef short s16x8 __attribute__((ext_vector_type(8)));
typedef float f32x4 __attribute__((ext_vector_type(4)));

// ---------------- Kernel 0: pack W into B-fragment layout ----------------
// Record r (0..6143): col=r&15, quad=(r>>4)&3, kb=r>>6. 16B record holds
// bf16 W[kb*32+quad*8+j][col], j=0..7 (zero for col>=10). Lane `l` of
// K-block kb then reads record kb*64+l with ONE coalesced dwordx4.
__global__ __launch_bounds__(256) void k0_pack(
    const float* __restrict__ W, unsigned short* __restrict__ pwg)
{
    const int r = blockIdx.x * 256 + threadIdx.x;   // 0..6143
    const int col  = r & 15;
    const int quad = (r >> 4) & 3;
    const int kb   = r >> 6;
    union { unsigned short us[8]; uint4 v; } rec;
#pragma unroll
    for (int j = 0; j < 8; ++j) {
        const int k = kb * 32 + quad * 8 + j;
        const float v = (col < KK) ? W[k * KK + col] : 0.0f;
        const __hip_bfloat16 h = __float2bfloat16(v);
        __builtin_memcpy(&rec.us[j], &h, 2);
    }
    ((uint4*)pwg)[r] = rec.v;
}

// ---------------- Kernel 1: MFMA logits + per-(n,b) losses ----------------
// grid = 768 blocks. Tile = (b, 16-n group): M-rows are 16 consecutive n's
// for ONE b, so the imgs pointer is lane-uniform per quad (L1 broadcast, no
// per-row imgs streaming). 8 waves = 8 K-splits; 12 mfma_16x16x32_bf16 steps
// each; A built on the fly (clip(imgs+deltas)->bf16); B-frags are single
// coalesced 16B loads from packed W. LDS split-K reduce + epilogue.
__global__ __launch_bounds__(512) void k1_mfma(
    const float* __restrict__ imgs,    // (128, 3072)
    const float* __restrict__ deltas,  // (96, 128, 3072)
    const unsigned short* __restrict__ pwg,
    const float* __restrict__ bias,    // (10)
    const int*   __restrict__ labels,  // (128)
    float* __restrict__ l1_ws,         // (128, 96)
    float* __restrict__ l2_ws)         // (128, 96)
{
    const int lane = threadIdx.x & 63;
    const int wv   = threadIdx.x >> 6;      // 0..7 = K-split
    const int tile = blockIdx.x;            // 0..767
    const int b    = tile & 127;
    const int n0   = (tile >> 7) * 16;
    const int m    = lane & 15;             // A row within tile -> n = n0+m
    const int quad = lane >> 4;

    const float* ap = deltas + ((size_t)(n0 + m) * BB + b) * DD + wv * (KST * 32) + quad * 8;
    const float* ip = imgs   + (size_t)b * DD + wv * (KST * 32) + quad * 8;  // lane-uniform per quad
    const unsigned short* wp = pwg + ((size_t)(wv * KST) * 64 + lane) * 8;

    f32x4 acc = {0.f, 0.f, 0.f, 0.f};
#pragma unroll 2
    for (int s = 0; s < KST; ++s) {
        const float4 d0 = *(const float4*)(ap);
        const float4 d1 = *(const float4*)(ap + 4);
        const float4 i0 = *(const float4*)(ip);
        const float4 i1 = *(const float4*)(ip + 4);
        const s16x8 bfrag = *(const s16x8*)(wp);
        float x[8];
        x[0] = d0.x + i0.x; x[1] = d0.y + i0.y; x[2] = d0.z + i0.z; x[3] = d0.w + i0.w;
        x[4] = d1.x + i1.x; x[5] = d1.y + i1.y; x[6] = d1.z + i1.z; x[7] = d1.w + i1.w;
        s16x8 afrag;
#pragma unroll
        for (int j = 0; j < 8; ++j) {
            const float xc = fminf(fmaxf(x[j], 0.f), 1.f);
            const __hip_bfloat16 h = __float2bfloat16(xc);
            unsigned short us; __builtin_memcpy(&us, &h, 2);
            afrag[j] = (short)us;
        }
        acc = __builtin_amdgcn_mfma_f32_16x16x32_bf16(afrag, bfrag, acc, 0, 0, 0);
        ap += 32; ip += 32; wp += 512;
    }

    // C layout (m89-verified): class col = lane&15, M-row = quad*4 + reg.
    __shared__ float sred[SPL][16][16];     // 8 KB
#pragma unroll
    for (int reg = 0; reg < 4; ++reg)
        sred[wv][quad * 4 + reg][m] = acc[reg];
    __syncthreads();

    if (wv == 0 && lane < 16) {
        const int rr = lane;                // tile row -> n = n0+rr
        float lg[KK];
#pragma unroll
        for (int k = 0; k < KK; ++k) {
            float s = 0.f;
#pragma unroll
            for (int sp = 0; sp < SPL; ++sp) s += sred[sp][rr][k];
            lg[k] = s + bias[k];
        }
        // top-1 (first max -> lower index on ties, matches lax.top_k)
        int top1 = 0; float m1 = lg[0];
#pragma unroll
        for (int k = 1; k < KK; ++k) if (lg[k] > m1) { m1 = lg[k]; top1 = k; }
        int sec = (top1 == 0) ? 1 : 0; float m2 = lg[sec];
#pragma unroll
        for (int k = 0; k < KK; ++k)
            if (k != top1 && lg[k] > m2) { m2 = lg[k]; sec = k; }
        float se = 0.f;
#pragma unroll
        for (int k = 0; k < KK; ++k) se += expf(lg[k] - m1);
        const float lse = m1 + logf(se);
        const int lab = labels[b];
        const float loss1 = lse - lg[lab];
        const float loss2 = (top1 == lab) ? (lse - lg[sec]) : -10000.0f;
        const int n = n0 + rr;
        l1_ws[b * NN + n] = loss1;
        l2_ws[b * NN + n] = loss2;
    }
}

// ------- Kernel 2: stable rank-ind selection + final mean (1 block) -------
__global__ __launch_bounds__(1024) void k2_final(
    const float* __restrict__ l1_ws, const float* __restrict__ l2_ws,
    const int* __restrict__ ind_p, float* __restrict__ out)
{
    const int t = threadIdx.x;           // 0..1023
    __shared__ float sdiff[BB * NN];     // 48 KB
    __shared__ float sl2[BB * NN];       // 48 KB
    __shared__ float ssel[BB];
    __shared__ float wpart[16];

    float suml1 = 0.f;
#pragma unroll
    for (int r = 0; r < 12; ++r) {       // 12288 / 1024
        const int p = t + r * 1024;
        const float a = l1_ws[p];
        const float c = l2_ws[p];
        suml1 += a;
        sdiff[p] = a - c;
        sl2[p]   = c;
    }
    __syncthreads();

    const int ind = ind_p[0];
#pragma unroll
    for (int r = 0; r < 12; ++r) {
        const int p = t + r * 1024;
        const int b = p / NN;
        const int n = p - b * NN;
        const float d = sdiff[p];
        int rank = 0;
        const float* row = sdiff + b * NN;
        for (int j = 0; j < NN; ++j) {
            const float dj = row[j];
            rank += (dj < d) || (dj == d && j < n);   // stable argsort
        }
        if (rank == ind) ssel[b] = sl2[p];
    }

    // block sum of suml1
#pragma unroll
    for (int off = 32; off >= 1; off >>= 1) suml1 += __shfl_down(suml1, off, 64);
    if ((t & 63) == 0) wpart[t >> 6] = suml1;
    __syncthreads();
    if (t < 64) {
        float s  = (t < 16) ? wpart[t] : 0.f;
#pragma unroll
        for (int off = 8; off >= 1; off >>= 1) s += __shfl_down(s, off, 64);
        float se = ssel[t] + ssel[t + 64];
#pragma unroll
        for (int off = 32; off >= 1; off >>= 1) se += __shfl_down(se, off, 64);
        if (t == 0)
            out[0] = s / (96.0f * 128.0f) - se / 128.0f;
    }
}

extern "C" void kernel_launch(void* const* d_in, const int* in_sizes, int n_in,
                              void* d_out, int out_size, void* d_ws, size_t ws_size,
                              hipStream_t stream) {
    const float* imgs   = (const float*)d_in[0];
    const float* deltas = (const float*)d_in[1];
    const float* W      = (const float*)d_in[2];
    const float* bias   = (const float*)d_in[3];
    const int*   labels = (const int*)d_in[4];
    const int*   ind    = (const int*)d_in[5];
    float* out = (float*)d_out;

    float* l1_ws = (float*)d_ws;                   // 12288 floats
    float* l2_ws = l1_ws + NN * BB;                // 12288 floats
    unsigned short* pwg = (unsigned short*)(l2_ws + NN * BB);  // 96 KB packed W

    k0_pack<<<dim3(24), dim3(256), 0, stream>>>(W, pwg);
    k1_mfma<<<dim3(768), dim3(512), 0, stream>>>(
        imgs, deltas, pwg, bias, labels, l1_ws, l2_ws);
    k2_final<<<dim3(1), dim3(1024), 0, stream>>>(l1_ws, l2_ws, ind, out);
}